// Round 3
// baseline (386.336 us; speedup 1.0000x reference)
//
#include <hip/hip_runtime.h>

#define DEVI __device__ __forceinline__

typedef __bf16 v8bf __attribute__((ext_vector_type(8)));
typedef float  v4f  __attribute__((ext_vector_type(4)));
typedef short  v4s  __attribute__((ext_vector_type(4)));

DEVI unsigned short f2bf(float f) {
  unsigned u = __builtin_bit_cast(unsigned, f);
  u += 0x7fffu + ((u >> 16) & 1u);
  return (unsigned short)(u >> 16);
}
DEVI v4f MFMA32(v8bf a, v8bf b, v4f c) {
  return __builtin_amdgcn_mfma_f32_16x16x32_bf16(a, b, c, 0, 0, 0);
}
DEVI v8bf ldfrag(const unsigned short* p) {
  return __builtin_bit_cast(v8bf, *(const uint4*)p);
}
DEVI v4s ld4s(const unsigned short* p) {
  return __builtin_bit_cast(v4s, *(const uint2*)p);
}

#if __has_builtin(__builtin_amdgcn_mfma_f32_16x16x16bf16_1k)
#define HAVE_MFMA16 1
DEVI v4f MFMA16(v4s a, v4s b, v4f c) {
  return __builtin_amdgcn_mfma_f32_16x16x16bf16_1k(a, b, c, 0, 0, 0);
}
#else
#define HAVE_MFMA16 0
#endif

// ---------------------------------------------------------------------------
// fp32 -> bf16 conversion of X (4,2,1024,512) and Wq/Wk/Wv/Wo (512x512 each).
// ---------------------------------------------------------------------------
__global__ __launch_bounds__(256) void convert_kernel(
    const float* __restrict__ X, const float* __restrict__ Wq,
    const float* __restrict__ Wk, const float* __restrict__ Wv,
    const float* __restrict__ Wo, unsigned short* __restrict__ dst)
{
  int t = blockIdx.x * 256 + threadIdx.x;
  int idx = t * 4;
  const float* src;
  if (idx < 4194304) {
    src = X + idx;
  } else {
    int u = idx - 4194304;
    int w = u >> 18;
    const float* W = (w == 0) ? Wq : (w == 1) ? Wk : (w == 2) ? Wv : Wo;
    src = W + (u & 262143);
  }
  float4 f = *(const float4*)src;
  ushort4 o;
  o.x = f2bf(f.x); o.y = f2bf(f.y); o.z = f2bf(f.z); o.w = f2bf(f.w);
  *(ushort4*)&dst[idx] = o;
}

// ---------------------------------------------------------------------------
// C[m][n] = sum_k A[m][k] * W[n][k] + bias[n]     (BT GEMM, M=8192 N=512 K=512)
// 128x128 tile, 4 waves. OUTM=0 bf16 row-major; grid.z==2 writes V transposed
// into VT[((bs*8+h)*64+hd)*1024 + t]. OUTM=1: fp32 row-major out.
// ---------------------------------------------------------------------------
template<int OUTM>
__global__ __launch_bounds__(256) void gemm_bt(
    const unsigned short* __restrict__ A,
    const unsigned short* __restrict__ W0, const unsigned short* __restrict__ W1,
    const unsigned short* __restrict__ W2,
    const float* __restrict__ b0, const float* __restrict__ b1, const float* __restrict__ b2,
    void* __restrict__ C0, void* __restrict__ C1, void* __restrict__ C2)
{
  const int K = 512, N = 512;
  __shared__ unsigned short sA[128][72];
  __shared__ unsigned short sB[128][72];
  const int z = blockIdx.z;
  const unsigned short* W = (z == 0) ? W0 : (z == 1) ? W1 : W2;
  const float* bias = (z == 0) ? b0 : (z == 1) ? b1 : b2;
  void* C = (z == 0) ? C0 : (z == 1) ? C1 : C2;

  const int tid = threadIdx.x;
  const int lane = tid & 63, wave = tid >> 6;
  const int l15 = lane & 15, quad = lane >> 4;
  const int wm = (wave >> 1) * 64, wn = (wave & 1) * 64;
  const int mbase = blockIdx.y * 128, nbase = blockIdx.x * 128;

  v4f acc[4][4] = {};

  for (int kt = 0; kt < K; kt += 64) {
    __syncthreads();
#pragma unroll
    for (int i = 0; i < 4; i++) {
      int c = tid + 256 * i;
      int row = c >> 3, c8 = (c & 7) * 8;
      *(uint4*)&sA[row][c8] = *(const uint4*)&A[(size_t)(mbase + row) * K + kt + c8];
      *(uint4*)&sB[row][c8] = *(const uint4*)&W[(size_t)(nbase + row) * K + kt + c8];
    }
    __syncthreads();
#pragma unroll
    for (int s = 0; s < 2; s++) {
      v8bf af[4], bf[4];
#pragma unroll
      for (int i = 0; i < 4; i++) af[i] = ldfrag(&sA[wm + i * 16 + l15][s * 32 + quad * 8]);
#pragma unroll
      for (int j = 0; j < 4; j++) bf[j] = ldfrag(&sB[wn + j * 16 + l15][s * 32 + quad * 8]);
#pragma unroll
      for (int i = 0; i < 4; i++)
#pragma unroll
        for (int j = 0; j < 4; j++)
          acc[i][j] = MFMA32(af[i], bf[j], acc[i][j]);
    }
  }

#pragma unroll
  for (int i = 0; i < 4; i++)
#pragma unroll
    for (int j = 0; j < 4; j++) {
      int row0 = mbase + wm + i * 16 + quad * 4;
      int col = nbase + wn + j * 16 + l15;
      float v[4];
#pragma unroll
      for (int r = 0; r < 4; r++) v[r] = acc[i][j][r] + bias[col];
      if (OUTM == 1) {
#pragma unroll
        for (int r = 0; r < 4; r++) ((float*)C)[(size_t)(row0 + r) * N + col] = v[r];
      } else if (z == 2) {
        int bs = row0 >> 10, t0 = row0 & 1023;
        int hh = col >> 6, hd = col & 63;
        ushort4 o;
        o.x = f2bf(v[0]); o.y = f2bf(v[1]); o.z = f2bf(v[2]); o.w = f2bf(v[3]);
        *(ushort4*)&((unsigned short*)C)[(size_t)((bs * 8 + hh) * 64 + hd) * 1024 + t0] = o;
      } else {
#pragma unroll
        for (int r = 0; r < 4; r++)
          ((unsigned short*)C)[(size_t)(row0 + r) * N + col] = f2bf(v[r]);
      }
    }
}

// ---------------------------------------------------------------------------
// stats: l[d][b][h][q] = sum_k exp(scale * (Q_d . K_{1-d}))   (fixed max = 0)
// split-k x4 (grid 2048), atomicAdd into zeroed lsum; register double-buffer.
// ---------------------------------------------------------------------------
__global__ __launch_bounds__(256, 4) void stats_kernel(
    const unsigned short* __restrict__ Qg, const unsigned short* __restrict__ Kg,
    float* __restrict__ lsum)
{
  const int bb = blockIdx.x & 511;
  const int kseg = blockIdx.x >> 9;
  const int pair = bb & 31;
  const int b = pair >> 3, h = pair & 7;
  const int qt = bb >> 5;
  const int tid = threadIdx.x;
  const int lane = tid & 63, wave = tid >> 6;
  const int l15 = lane & 15, quad = lane >> 4;
  const int qbase = (qt * 4 + wave) * 16;
  const float scale = 0.125f;

  v8bf qf[2][2];
#pragma unroll
  for (int d = 0; d < 2; d++)
#pragma unroll
    for (int s = 0; s < 2; s++) {
      int qrow = (b * 2 + d) * 1024 + qbase + l15;
      qf[d][s] = ldfrag(&Qg[(size_t)qrow * 512 + h * 64 + s * 32 + quad * 8]);
    }

  const unsigned short* kp[2];
#pragma unroll
  for (int d = 0; d < 2; d++)
    kp[d] = Kg + (size_t)((b * 2 + (1 - d)) * 1024 + l15) * 512 + h * 64 + quad * 8;

  const int c0 = kseg * 8;
  v8bf kc[2][2][2];
#pragma unroll
  for (int s = 0; s < 2; s++)
#pragma unroll
    for (int d = 0; d < 2; d++)
#pragma unroll
      for (int jt = 0; jt < 2; jt++)
        kc[s][d][jt] = ldfrag(kp[d] + (size_t)(c0 * 32 + jt * 16) * 512 + s * 32);

  float lacc[2] = {0.f, 0.f};

#pragma unroll 2
  for (int c = c0; c < c0 + 8; c++) {
    int cn = (c + 1 < c0 + 8) ? c + 1 : c0;
    v8bf kn[2][2][2];
#pragma unroll
    for (int s = 0; s < 2; s++)
#pragma unroll
      for (int d = 0; d < 2; d++)
#pragma unroll
        for (int jt = 0; jt < 2; jt++)
          kn[s][d][jt] = ldfrag(kp[d] + (size_t)(cn * 32 + jt * 16) * 512 + s * 32);

    v4f acc[2][2] = {};
#pragma unroll
    for (int s = 0; s < 2; s++)
#pragma unroll
      for (int d = 0; d < 2; d++)
#pragma unroll
        for (int jt = 0; jt < 2; jt++)
          acc[d][jt] = MFMA32(kc[s][d][jt], qf[d][s], acc[d][jt]);
#pragma unroll
    for (int d = 0; d < 2; d++)
#pragma unroll
      for (int jt = 0; jt < 2; jt++)
#pragma unroll
        for (int r = 0; r < 4; r++)
          lacc[d] += __expf(acc[d][jt][r] * scale);

#pragma unroll
    for (int s = 0; s < 2; s++)
#pragma unroll
      for (int d = 0; d < 2; d++)
#pragma unroll
        for (int jt = 0; jt < 2; jt++)
          kc[s][d][jt] = kn[s][d][jt];
  }

#pragma unroll
  for (int d = 0; d < 2; d++) {
    float v = lacc[d];
    v += __shfl_xor(v, 16);
    v += __shfl_xor(v, 32);
    if (quad == 0)
      atomicAdd(&lsum[((d * 4 + b) * 8 + h) * 1024 + qbase + l15], v);
  }
}

// ---------------------------------------------------------------------------
// main attention: scores via K·Q^T (lane: q=l15, k=quad*4+r), in-register
// competitive combine, PV via 16x16x16 MFMA.  Register double-buffered
// global loads (grid-limited occupancy -> VGPRs are free).
// ---------------------------------------------------------------------------
__global__ __launch_bounds__(256, 2) void attn_kernel(
    const unsigned short* __restrict__ Qg, const unsigned short* __restrict__ Kg,
    const unsigned short* __restrict__ VTg, const float* __restrict__ lsum,
    unsigned short* __restrict__ Hc)
{
  const int pair = blockIdx.x & 31;
  const int b = pair >> 3, h = pair & 7;
  const int qt = blockIdx.x >> 5;
  const int tid = threadIdx.x;
  const int lane = tid & 63, wave = tid >> 6;
  const int l15 = lane & 15, quad = lane >> 4;
  const int qbase = (qt * 4 + wave) * 16;
  const float scale = 0.125f;

  v8bf qf[2][2];
  float ll[2];
#pragma unroll
  for (int d = 0; d < 2; d++) {
#pragma unroll
    for (int s = 0; s < 2; s++) {
      int qrow = (b * 2 + d) * 1024 + qbase + l15;
      qf[d][s] = ldfrag(&Qg[(size_t)qrow * 512 + h * 64 + s * 32 + quad * 8]);
    }
    ll[d] = __logf(lsum[((d * 4 + b) * 8 + h) * 1024 + qbase + l15]);
  }

  const unsigned short* kp[2];
  const unsigned short* vp[2];
#pragma unroll
  for (int d = 0; d < 2; d++) {
    kp[d] = Kg + (size_t)((b * 2 + (1 - d)) * 1024 + l15) * 512 + h * 64 + quad * 8;
    vp[d] = VTg + (size_t)(((b * 2 + (1 - d)) * 8 + h) * 64 + l15) * 1024 + quad * 4;
  }

  // prefetch c = 0
  v8bf kc[2][2][2];
  v4s vc[2][2][4];
#pragma unroll
  for (int s = 0; s < 2; s++)
#pragma unroll
    for (int d = 0; d < 2; d++)
#pragma unroll
      for (int jt = 0; jt < 2; jt++)
        kc[s][d][jt] = ldfrag(kp[d] + (size_t)(jt * 16) * 512 + s * 32);
#pragma unroll
  for (int d = 0; d < 2; d++)
#pragma unroll
    for (int jt = 0; jt < 2; jt++)
#pragma unroll
      for (int nt = 0; nt < 4; nt++)
        vc[d][jt][nt] = ld4s(vp[d] + (size_t)(nt * 16) * 1024 + jt * 16);

  v4f oacc[2][4] = {};

#pragma unroll 2
  for (int c = 0; c < 32; c++) {
    const int cn = (c + 1) & 31;   // wraps; re-loads c=0 data on last iter (L2 hit)
    v8bf kn[2][2][2];
    v4s vn[2][2][4];
#pragma unroll
    for (int s = 0; s < 2; s++)
#pragma unroll
      for (int d = 0; d < 2; d++)
#pragma unroll
        for (int jt = 0; jt < 2; jt++)
          kn[s][d][jt] = ldfrag(kp[d] + (size_t)(cn * 32 + jt * 16) * 512 + s * 32);
#pragma unroll
    for (int d = 0; d < 2; d++)
#pragma unroll
      for (int jt = 0; jt < 2; jt++)
#pragma unroll
        for (int nt = 0; nt < 4; nt++)
          vn[d][jt][nt] = ld4s(vp[d] + (size_t)(nt * 16) * 1024 + cn * 32 + jt * 16);

    v4f acc[2][2] = {};
#pragma unroll
    for (int s = 0; s < 2; s++)
#pragma unroll
      for (int d = 0; d < 2; d++)
#pragma unroll
        for (int jt = 0; jt < 2; jt++)
          acc[d][jt] = MFMA32(kc[s][d][jt], qf[d][s], acc[d][jt]);

#if HAVE_MFMA16
    v4s af[2][2];
#pragma unroll
    for (int jt = 0; jt < 2; jt++)
#pragma unroll
      for (int r = 0; r < 4; r++) {
        float p0 = __expf(fmaf(acc[0][jt][r], scale, -ll[0]));
        float p1 = __expf(fmaf(acc[1][jt][r], scale, -ll[1]));
        float ri = __builtin_amdgcn_rcpf(p0 + p1 + 1e-6f);
        af[0][jt][r] = (short)f2bf(p0 * ri);
        af[1][jt][r] = (short)f2bf(p1 * ri);
      }
#pragma unroll
    for (int d = 0; d < 2; d++)
#pragma unroll
      for (int jt = 0; jt < 2; jt++)
#pragma unroll
        for (int nt = 0; nt < 4; nt++)
          oacc[d][nt] = MFMA16(af[d][jt], vc[d][jt][nt], oacc[d][nt]);
#else
    // fallback: shuffle-transform to 16x16x32 A-operand layout
    float cb[2][2][4];
#pragma unroll
    for (int jt = 0; jt < 2; jt++)
#pragma unroll
      for (int r = 0; r < 4; r++) {
        float p0 = __expf(fmaf(acc[0][jt][r], scale, -ll[0]));
        float p1 = __expf(fmaf(acc[1][jt][r], scale, -ll[1]));
        float ri = __builtin_amdgcn_rcpf(p0 + p1 + 1e-6f);
        cb[0][jt][r] = p0 * ri;
        cb[1][jt][r] = p1 * ri;
      }
#pragma unroll
    for (int d = 0; d < 2; d++) {
      v8bf a;
#pragma unroll
      for (int jj = 0; jj < 8; jj++) {
        int r = jj & 3;
        int k = quad * 8 + jj;
        int src = l15 + 16 * ((k >> 2) & 3);
        float v0 = __shfl(cb[d][0][r], src);
        float v1 = __shfl(cb[d][1][r], src);
        float v = (quad < 2) ? v0 : v1;
        a[jj] = __builtin_bit_cast(__bf16, f2bf(v));
      }
#pragma unroll
      for (int nt = 0; nt < 4; nt++) {
        v8bf vf = ldfrag(vp[d] - quad * 4 + (size_t)(nt * 16) * 1024 + c * 32 + quad * 8);
        oacc[d][nt] = MFMA32(a, vf, oacc[d][nt]);
      }
    }
#endif

#pragma unroll
    for (int s = 0; s < 2; s++)
#pragma unroll
      for (int d = 0; d < 2; d++)
#pragma unroll
        for (int jt = 0; jt < 2; jt++)
          kc[s][d][jt] = kn[s][d][jt];
#pragma unroll
    for (int d = 0; d < 2; d++)
#pragma unroll
      for (int jt = 0; jt < 2; jt++)
#pragma unroll
        for (int nt = 0; nt < 4; nt++)
          vc[d][jt][nt] = vn[d][jt][nt];
  }

#pragma unroll
  for (int d = 0; d < 2; d++)
#pragma unroll
    for (int nt = 0; nt < 4; nt++)
#pragma unroll
      for (int r = 0; r < 4; r++) {
        int row = (b * 2 + d) * 1024 + qbase + quad * 4 + r;
        int col = h * 64 + nt * 16 + l15;
        Hc[(size_t)row * 512 + col] = f2bf(oacc[d][nt][r]);
      }
}

// ---------------------------------------------------------------------------
// LayerNorm (over D=512) + gate + residual.  One block per row.
// ---------------------------------------------------------------------------
__global__ __launch_bounds__(256) void ln_kernel(
    const float* __restrict__ P, const float* __restrict__ hidden,
    const float* __restrict__ ln_g, const float* __restrict__ ln_b,
    const float* __restrict__ gate, float* __restrict__ out)
{
  const int row = blockIdx.x;
  const int s = (row >> 10) & 1;
  const int tid = threadIdx.x;
  const int d0 = tid * 2;
  float2 x = *(const float2*)&P[(size_t)row * 512 + d0];
  float s1 = x.x + x.y;
  float s2 = x.x * x.x + x.y * x.y;
#pragma unroll
  for (int m = 1; m < 64; m <<= 1) { s1 += __shfl_xor(s1, m); s2 += __shfl_xor(s2, m); }
  __shared__ float r1[4], r2[4];
  if ((tid & 63) == 0) { r1[tid >> 6] = s1; r2[tid >> 6] = s2; }
  __syncthreads();
  s1 = r1[0] + r1[1] + r1[2] + r1[3];
  s2 = r2[0] + r2[1] + r2[2] + r2[3];
  float mu = s1 * (1.f / 512.f);
  float var = s2 * (1.f / 512.f) - mu * mu;
  float rs = rsqrtf(var + 1e-5f);
  float al = gate[s];
  float2 hv = *(const float2*)&hidden[(size_t)row * 512 + d0];
  float2 o;
  o.x = hv.x + ((x.x - mu) * rs * ln_g[s * 512 + d0]     + ln_b[s * 512 + d0])     * al;
  o.y = hv.y + ((x.y - mu) * rs * ln_g[s * 512 + d0 + 1] + ln_b[s * 512 + d0 + 1]) * al;
  *(float2*)&out[(size_t)row * 512 + d0] = o;
}

// ---------------------------------------------------------------------------
extern "C" void kernel_launch(void* const* d_in, const int* in_sizes, int n_in,
                              void* d_out, int out_size, void* d_ws, size_t ws_size,
                              hipStream_t stream)
{
  const float* hidden = (const float*)d_in[0];
  const float* Wq = (const float*)d_in[1];
  const float* bq = (const float*)d_in[2];
  const float* Wk = (const float*)d_in[3];
  const float* bk = (const float*)d_in[4];
  const float* Wv = (const float*)d_in[5];
  const float* bv = (const float*)d_in[6];
  const float* Wo = (const float*)d_in[7];
  const float* bo = (const float*)d_in[8];
  const float* ln_g = (const float*)d_in[9];
  const float* ln_b = (const float*)d_in[10];
  const float* gate = (const float*)d_in[11];

  unsigned short* U = (unsigned short*)d_ws;
  unsigned short* Xbf = U;
  unsigned short* Wqb = U + 4194304;
  unsigned short* Wkb = U + 4456448;
  unsigned short* Wvb = U + 4718592;
  unsigned short* Wob = U + 4980736;
  unsigned short* Qg  = U + 5242880;
  unsigned short* Kg  = U + 9437184;
  unsigned short* VT  = U + 13631488;
  unsigned short* Hc  = U + 17825792;
  float* lsum = (float*)((char*)d_ws + 44040192);
  float* P    = (float*)((char*)d_ws + 44302336);

  convert_kernel<<<dim3(5120), 256, 0, stream>>>(hidden, Wq, Wk, Wv, Wo, Xbf);
  gemm_bt<0><<<dim3(4, 64, 3), 256, 0, stream>>>(Xbf, Wqb, Wkb, Wvb, bq, bk, bv, Qg, Kg, VT);
  hipMemsetAsync(lsum, 0, 262144, stream);
  stats_kernel<<<dim3(2048), 256, 0, stream>>>(Qg, Kg, lsum);
  attn_kernel<<<dim3(512), 256, 0, stream>>>(Qg, Kg, VT, lsum, Hc);
  gemm_bt<1><<<dim3(4, 64, 1), 256, 0, stream>>>(Hc, Wob, Wob, Wob, bo, bo, bo, P, P, P);
  ln_kernel<<<dim3(8192), 256, 0, stream>>>(P, hidden, ln_g, ln_b, gate, (float*)d_out);
}

// Round 4
// 270.469 us; speedup vs baseline: 1.4284x; 1.4284x over previous
//
#include <hip/hip_runtime.h>

#define DEVI __device__ __forceinline__

typedef __bf16 v8bf __attribute__((ext_vector_type(8)));
typedef float  v4f  __attribute__((ext_vector_type(4)));
typedef short  v4s  __attribute__((ext_vector_type(4)));

DEVI unsigned short f2bf(float f) {
  unsigned u = __builtin_bit_cast(unsigned, f);
  u += 0x7fffu + ((u >> 16) & 1u);
  return (unsigned short)(u >> 16);
}
DEVI v4f MFMA32(v8bf a, v8bf b, v4f c) {
  return __builtin_amdgcn_mfma_f32_16x16x32_bf16(a, b, c, 0, 0, 0);
}
DEVI v8bf ldfrag(const unsigned short* p) {
  return __builtin_bit_cast(v8bf, *(const uint4*)p);
}
DEVI v4s ld4s(const unsigned short* p) {
  return __builtin_bit_cast(v4s, *(const uint2*)p);
}

#if __has_builtin(__builtin_amdgcn_mfma_f32_16x16x16bf16_1k)
#define HAVE_MFMA16 1
DEVI v4f MFMA16(v4s a, v4s b, v4f c) {
  return __builtin_amdgcn_mfma_f32_16x16x16bf16_1k(a, b, c, 0, 0, 0);
}
#else
#define HAVE_MFMA16 0
#endif

// ---------------------------------------------------------------------------
// fp32 -> bf16 conversion of X (4,2,1024,512) and Wq/Wk/Wv/Wo (512x512 each).
// ---------------------------------------------------------------------------
__global__ __launch_bounds__(256) void convert_kernel(
    const float* __restrict__ X, const float* __restrict__ Wq,
    const float* __restrict__ Wk, const float* __restrict__ Wv,
    const float* __restrict__ Wo, unsigned short* __restrict__ dst)
{
  int t = blockIdx.x * 256 + threadIdx.x;
  int idx = t * 4;
  const float* src;
  if (idx < 4194304) {
    src = X + idx;
  } else {
    int u = idx - 4194304;
    int w = u >> 18;
    const float* W = (w == 0) ? Wq : (w == 1) ? Wk : (w == 2) ? Wv : Wo;
    src = W + (u & 262143);
  }
  float4 f = *(const float4*)src;
  ushort4 o;
  o.x = f2bf(f.x); o.y = f2bf(f.y); o.z = f2bf(f.z); o.w = f2bf(f.w);
  *(ushort4*)&dst[idx] = o;
}

// ---------------------------------------------------------------------------
// C[m][n] = sum_k A[m][k] * W[n][k] + bias[n]     (BT GEMM, M=8192 N=512 K=512)
// 128x128 tile, 4 waves. OUTM=0 bf16 row-major; grid.z==2 writes V transposed
// into VT[((bs*8+h)*64+hd)*1024 + t]. OUTM=1: fp32 row-major out.
// ---------------------------------------------------------------------------
template<int OUTM>
__global__ __launch_bounds__(256) void gemm_bt(
    const unsigned short* __restrict__ A,
    const unsigned short* __restrict__ W0, const unsigned short* __restrict__ W1,
    const unsigned short* __restrict__ W2,
    const float* __restrict__ b0, const float* __restrict__ b1, const float* __restrict__ b2,
    void* __restrict__ C0, void* __restrict__ C1, void* __restrict__ C2)
{
  const int K = 512, N = 512;
  __shared__ unsigned short sA[128][72];
  __shared__ unsigned short sB[128][72];
  const int z = blockIdx.z;
  const unsigned short* W = (z == 0) ? W0 : (z == 1) ? W1 : W2;
  const float* bias = (z == 0) ? b0 : (z == 1) ? b1 : b2;
  void* C = (z == 0) ? C0 : (z == 1) ? C1 : C2;

  const int tid = threadIdx.x;
  const int lane = tid & 63, wave = tid >> 6;
  const int l15 = lane & 15, quad = lane >> 4;
  const int wm = (wave >> 1) * 64, wn = (wave & 1) * 64;
  const int mbase = blockIdx.y * 128, nbase = blockIdx.x * 128;

  v4f acc[4][4] = {};

  for (int kt = 0; kt < K; kt += 64) {
    __syncthreads();
#pragma unroll
    for (int i = 0; i < 4; i++) {
      int c = tid + 256 * i;
      int row = c >> 3, c8 = (c & 7) * 8;
      *(uint4*)&sA[row][c8] = *(const uint4*)&A[(size_t)(mbase + row) * K + kt + c8];
      *(uint4*)&sB[row][c8] = *(const uint4*)&W[(size_t)(nbase + row) * K + kt + c8];
    }
    __syncthreads();
#pragma unroll
    for (int s = 0; s < 2; s++) {
      v8bf af[4], bf[4];
#pragma unroll
      for (int i = 0; i < 4; i++) af[i] = ldfrag(&sA[wm + i * 16 + l15][s * 32 + quad * 8]);
#pragma unroll
      for (int j = 0; j < 4; j++) bf[j] = ldfrag(&sB[wn + j * 16 + l15][s * 32 + quad * 8]);
#pragma unroll
      for (int i = 0; i < 4; i++)
#pragma unroll
        for (int j = 0; j < 4; j++)
          acc[i][j] = MFMA32(af[i], bf[j], acc[i][j]);
    }
  }

#pragma unroll
  for (int i = 0; i < 4; i++)
#pragma unroll
    for (int j = 0; j < 4; j++) {
      int row0 = mbase + wm + i * 16 + quad * 4;
      int col = nbase + wn + j * 16 + l15;
      float v[4];
#pragma unroll
      for (int r = 0; r < 4; r++) v[r] = acc[i][j][r] + bias[col];
      if (OUTM == 1) {
#pragma unroll
        for (int r = 0; r < 4; r++) ((float*)C)[(size_t)(row0 + r) * N + col] = v[r];
      } else if (z == 2) {
        int bs = row0 >> 10, t0 = row0 & 1023;
        int hh = col >> 6, hd = col & 63;
        ushort4 o;
        o.x = f2bf(v[0]); o.y = f2bf(v[1]); o.z = f2bf(v[2]); o.w = f2bf(v[3]);
        *(ushort4*)&((unsigned short*)C)[(size_t)((bs * 8 + hh) * 64 + hd) * 1024 + t0] = o;
      } else {
#pragma unroll
        for (int r = 0; r < 4; r++)
          ((unsigned short*)C)[(size_t)(row0 + r) * N + col] = f2bf(v[r]);
      }
    }
}

// ---------------------------------------------------------------------------
// Fused competitive cross-attention (single kernel, two passes).
// Block = (b,h,64-row q-tile), 4 waves; wave w owns q rows [w*16, w*16+16),
// BOTH directions.  K/V tiles (64 keys, both streams) staged in LDS,
// cooperatively loaded (coalesced; global->VGPR prefetch of tile t+1 between
// ds_write and compute of tile t -- m97 pattern, data-dep forces early issue).
// Pass A: QK + exp-sum -> l[d] per q row (max fixed at 0; logits ~ +-2).
// Pass B: QK again, p=exp(s*scale - log l), competitive combine in-register
// (lane holds both dirs' score at same position), PV via 16x16x16 MFMA
// (score C-layout == A-operand layout -- no transform).
// ---------------------------------------------------------------------------
__global__ __launch_bounds__(256) void attn_kernel(
    const unsigned short* __restrict__ Qg, const unsigned short* __restrict__ Kg,
    const unsigned short* __restrict__ VTg, unsigned short* __restrict__ Hc)
{
  __shared__ unsigned short sK[2][64][72];
  __shared__ unsigned short sV[2][64][72];

  const int pair = blockIdx.x & 31;   // h = pair&7 -> XCD L2 affinity
  const int b = pair >> 3, h = pair & 7;
  const int qt = blockIdx.x >> 5;
  const int tid = threadIdx.x;
  const int lane = tid & 63, wave = tid >> 6;
  const int l15 = lane & 15, quad = lane >> 4;
  const int qbase = qt * 64 + wave * 16;
  const float scale = 0.125f;

  // Q fragments, held for the whole kernel
  v8bf qf[2][2];
#pragma unroll
  for (int d = 0; d < 2; d++)
#pragma unroll
    for (int s = 0; s < 2; s++) {
      int qrow = (b * 2 + d) * 1024 + qbase + l15;
      qf[d][s] = ldfrag(&Qg[(size_t)qrow * 512 + h * 64 + s * 32 + quad * 8]);
    }

  // cooperative staging pattern: thread stages rows srow, srow+32
  const int srow = tid >> 3;
  const int scol = (tid & 7) * 8;
  const unsigned short* kgp[2];
  const unsigned short* vgp[2];
#pragma unroll
  for (int st = 0; st < 2; st++) {
    kgp[st] = Kg + (size_t)((b * 2 + st) * 1024) * 512 + h * 64;
    vgp[st] = VTg + (size_t)(((b * 2 + st) * 8 + h) * 64) * 1024;
  }

  // ---------------- pass A: l sums ----------------
  float lacc[2] = {0.f, 0.f};
  {
    uint4 kpre[2][2];
#pragma unroll
    for (int st = 0; st < 2; st++)
#pragma unroll
      for (int i = 0; i < 2; i++)
        kpre[st][i] = *(const uint4*)&kgp[st][(size_t)(srow + 32 * i) * 512 + scol];

    for (int kt = 0; kt < 16; kt++) {
      __syncthreads();
#pragma unroll
      for (int st = 0; st < 2; st++)
#pragma unroll
        for (int i = 0; i < 2; i++)
          *(uint4*)&sK[st][srow + 32 * i][scol] = kpre[st][i];
      if (kt < 15) {
#pragma unroll
        for (int st = 0; st < 2; st++)
#pragma unroll
          for (int i = 0; i < 2; i++)
            kpre[st][i] = *(const uint4*)&kgp[st][(size_t)((kt + 1) * 64 + srow + 32 * i) * 512 + scol];
      }
      __syncthreads();

      v4f acc[2][4] = {};
#pragma unroll
      for (int s = 0; s < 2; s++)
#pragma unroll
        for (int d = 0; d < 2; d++)
#pragma unroll
          for (int j = 0; j < 4; j++) {
            v8bf kf = ldfrag(&sK[1 - d][j * 16 + l15][s * 32 + quad * 8]);
            acc[d][j] = MFMA32(kf, qf[d][s], acc[d][j]);
          }
#pragma unroll
      for (int d = 0; d < 2; d++)
#pragma unroll
        for (int j = 0; j < 4; j++)
#pragma unroll
          for (int r = 0; r < 4; r++)
            lacc[d] += __expf(acc[d][j][r] * scale);
    }
  }
  float ll[2];
#pragma unroll
  for (int d = 0; d < 2; d++) {
    float v = lacc[d];
    v += __shfl_xor(v, 16);
    v += __shfl_xor(v, 32);
    ll[d] = __logf(v);
  }

  // ---------------- pass B: combine + PV ----------------
  v4f oacc[2][4] = {};
  {
    uint4 kpre[2][2], vpre[2][2];
#pragma unroll
    for (int st = 0; st < 2; st++)
#pragma unroll
      for (int i = 0; i < 2; i++) {
        kpre[st][i] = *(const uint4*)&kgp[st][(size_t)(srow + 32 * i) * 512 + scol];
        vpre[st][i] = *(const uint4*)&vgp[st][(size_t)(srow + 32 * i) * 1024 + scol];
      }

    for (int kt = 0; kt < 16; kt++) {
      __syncthreads();
#pragma unroll
      for (int st = 0; st < 2; st++)
#pragma unroll
        for (int i = 0; i < 2; i++) {
          *(uint4*)&sK[st][srow + 32 * i][scol] = kpre[st][i];
          *(uint4*)&sV[st][srow + 32 * i][scol] = vpre[st][i];
        }
      if (kt < 15) {
#pragma unroll
        for (int st = 0; st < 2; st++)
#pragma unroll
          for (int i = 0; i < 2; i++) {
            kpre[st][i] = *(const uint4*)&kgp[st][(size_t)((kt + 1) * 64 + srow + 32 * i) * 512 + scol];
            vpre[st][i] = *(const uint4*)&vgp[st][(size_t)(srow + 32 * i) * 1024 + (kt + 1) * 64 + scol];
          }
      }
      __syncthreads();

      v4f acc[2][4] = {};
#pragma unroll
      for (int s = 0; s < 2; s++)
#pragma unroll
        for (int d = 0; d < 2; d++)
#pragma unroll
          for (int j = 0; j < 4; j++) {
            v8bf kf = ldfrag(&sK[1 - d][j * 16 + l15][s * 32 + quad * 8]);
            acc[d][j] = MFMA32(kf, qf[d][s], acc[d][j]);
          }

#if HAVE_MFMA16
      v4s af[2][4];
#pragma unroll
      for (int j = 0; j < 4; j++)
#pragma unroll
        for (int r = 0; r < 4; r++) {
          float p0 = __expf(fmaf(acc[0][j][r], scale, -ll[0]));
          float p1 = __expf(fmaf(acc[1][j][r], scale, -ll[1]));
          float ri = __builtin_amdgcn_rcpf(p0 + p1 + 1e-6f);
          af[0][j][r] = (short)f2bf(p0 * ri);
          af[1][j][r] = (short)f2bf(p1 * ri);
        }
#pragma unroll
      for (int d = 0; d < 2; d++)
#pragma unroll
        for (int j = 0; j < 4; j++)
#pragma unroll
          for (int nt = 0; nt < 4; nt++) {
            v4s vf = ld4s(&sV[1 - d][nt * 16 + l15][j * 16 + quad * 4]);
            oacc[d][nt] = MFMA16(af[d][j], vf, oacc[d][nt]);
          }
#else
      float cb[2][4][4];
#pragma unroll
      for (int j = 0; j < 4; j++)
#pragma unroll
        for (int r = 0; r < 4; r++) {
          float p0 = __expf(fmaf(acc[0][j][r], scale, -ll[0]));
          float p1 = __expf(fmaf(acc[1][j][r], scale, -ll[1]));
          float ri = __builtin_amdgcn_rcpf(p0 + p1 + 1e-6f);
          cb[0][j][r] = p0 * ri;
          cb[1][j][r] = p1 * ri;
        }
#pragma unroll
      for (int kh = 0; kh < 2; kh++)
#pragma unroll
        for (int d = 0; d < 2; d++) {
          v8bf a;
#pragma unroll
          for (int jj = 0; jj < 8; jj++) {
            int src = l15 + 16 * ((quad & 1) * 2 + (jj >> 2));
            float s0 = __shfl(cb[d][kh * 2 + 0][jj & 3], src);
            float s1 = __shfl(cb[d][kh * 2 + 1][jj & 3], src);
            float v = (quad < 2) ? s0 : s1;
            a[jj] = __builtin_bit_cast(__bf16, f2bf(v));
          }
#pragma unroll
          for (int nt = 0; nt < 4; nt++) {
            v8bf vf = ldfrag(&sV[1 - d][nt * 16 + l15][kh * 32 + quad * 8]);
            oacc[d][nt] = MFMA32(a, vf, oacc[d][nt]);
          }
        }
#endif
    }
  }

#pragma unroll
  for (int d = 0; d < 2; d++)
#pragma unroll
    for (int nt = 0; nt < 4; nt++)
#pragma unroll
      for (int r = 0; r < 4; r++) {
        int row = (b * 2 + d) * 1024 + qbase + quad * 4 + r;
        int col = h * 64 + nt * 16 + l15;
        Hc[(size_t)row * 512 + col] = f2bf(oacc[d][nt][r]);
      }
}

// ---------------------------------------------------------------------------
// LayerNorm (over D=512) + gate + residual.  One block per row.
// ---------------------------------------------------------------------------
__global__ __launch_bounds__(256) void ln_kernel(
    const float* __restrict__ P, const float* __restrict__ hidden,
    const float* __restrict__ ln_g, const float* __restrict__ ln_b,
    const float* __restrict__ gate, float* __restrict__ out)
{
  const int row = blockIdx.x;
  const int s = (row >> 10) & 1;
  const int tid = threadIdx.x;
  const int d0 = tid * 2;
  float2 x = *(const float2*)&P[(size_t)row * 512 + d0];
  float s1 = x.x + x.y;
  float s2 = x.x * x.x + x.y * x.y;
#pragma unroll
  for (int m = 1; m < 64; m <<= 1) { s1 += __shfl_xor(s1, m); s2 += __shfl_xor(s2, m); }
  __shared__ float r1[4], r2[4];
  if ((tid & 63) == 0) { r1[tid >> 6] = s1; r2[tid >> 6] = s2; }
  __syncthreads();
  s1 = r1[0] + r1[1] + r1[2] + r1[3];
  s2 = r2[0] + r2[1] + r2[2] + r2[3];
  float mu = s1 * (1.f / 512.f);
  float var = s2 * (1.f / 512.f) - mu * mu;
  float rs = rsqrtf(var + 1e-5f);
  float al = gate[s];
  float2 hv = *(const float2*)&hidden[(size_t)row * 512 + d0];
  float2 o;
  o.x = hv.x + ((x.x - mu) * rs * ln_g[s * 512 + d0]     + ln_b[s * 512 + d0])     * al;
  o.y = hv.y + ((x.y - mu) * rs * ln_g[s * 512 + d0 + 1] + ln_b[s * 512 + d0 + 1]) * al;
  *(float2*)&out[(size_t)row * 512 + d0] = o;
}

// ---------------------------------------------------------------------------
extern "C" void kernel_launch(void* const* d_in, const int* in_sizes, int n_in,
                              void* d_out, int out_size, void* d_ws, size_t ws_size,
                              hipStream_t stream)
{
  const float* hidden = (const float*)d_in[0];
  const float* Wq = (const float*)d_in[1];
  const float* bq = (const float*)d_in[2];
  const float* Wk = (const float*)d_in[3];
  const float* bk = (const float*)d_in[4];
  const float* Wv = (const float*)d_in[5];
  const float* bv = (const float*)d_in[6];
  const float* Wo = (const float*)d_in[7];
  const float* bo = (const float*)d_in[8];
  const float* ln_g = (const float*)d_in[9];
  const float* ln_b = (const float*)d_in[10];
  const float* gate = (const float*)d_in[11];

  unsigned short* U = (unsigned short*)d_ws;
  unsigned short* Xbf = U;
  unsigned short* Wqb = U + 4194304;
  unsigned short* Wkb = U + 4456448;
  unsigned short* Wvb = U + 4718592;
  unsigned short* Wob = U + 4980736;
  unsigned short* Qg  = U + 5242880;
  unsigned short* Kg  = U + 9437184;
  unsigned short* VT  = U + 13631488;
  unsigned short* Hc  = U + 17825792;
  float* P    = (float*)((char*)d_ws + 44302336);

  convert_kernel<<<dim3(5120), 256, 0, stream>>>(hidden, Wq, Wk, Wv, Wo, Xbf);
  gemm_bt<0><<<dim3(4, 64, 3), 256, 0, stream>>>(Xbf, Wqb, Wkb, Wvb, bq, bk, bv, Qg, Kg, VT);
  attn_kernel<<<dim3(512), 256, 0, stream>>>(Qg, Kg, VT, Hc);
  gemm_bt<1><<<dim3(4, 64, 1), 256, 0, stream>>>(Hc, Wob, Wob, Wob, bo, bo, bo, P, P, P);
  ln_kernel<<<dim3(8192), 256, 0, stream>>>(P, hidden, ln_g, ln_b, gate, (float*)d_out);
}